// Round 3
// baseline (319.153 us; speedup 1.0000x reference)
//
#include <hip/hip_runtime.h>

typedef __attribute__((ext_vector_type(8))) short short8;
typedef __attribute__((ext_vector_type(4))) float floatx4;

// Problem constants
#define NEXP   36          // 12 tempers * 3 ops
#define NTOK   1024        // 128 batch * 8 patches
#define HOPS   4
#define PGRID  256         // persistent kernel grid (1 block/CU, all co-resident)

// Workspace layout (bytes)
#define OFF_STATE   0u          // 1024*256*4      = 1,048,576
#define OFF_W1B     1048576u    // 36*65536*2      = 4,718,592 (bf16, swizzled)
#define OFF_W2B     5767168u    // 36*65536*2      = 4,718,592
#define OFF_C1      10485760u   // 36*256*4        = 36,864
#define OFF_COUNTS  10522624u   // 4*36*4          = 576
#define OFF_LISTS   10523264u   // 4*36*1024*4     = 589,824
#define OFF_JOBS    11113088u   // 4*128*4         = 2,048
#define OFF_NJ      11115136u   // 4*4             = 16
#define OFF_BAR     11115152u   // 4               (end ~11.1 MB)

__device__ __forceinline__ unsigned short f2bf(float f) {
    unsigned u = __float_as_uint(f);
    u += 0x7FFFu + ((u >> 16) & 1u);   // round-to-nearest-even
    return (unsigned short)(u >> 16);
}

// ---------------------------------------------------------------------------
// PREP: one kernel, block-role partitioned.
//  blocks [0,2304)    : convert W1(first 256 rows)/W2 -> bf16 in B-frag layout
//                       Wb[e][kb][j][k32],  kb=k/32, k32=k%32
//  blocks [2304,2340) : c1[e][j] = b1[e][j] + sum_k emb[e][k]*W1[e][256+k][j]
//  blocks [2340,2404) : copy x -> state (f32)
//  block  2404        : routing + job compaction + barrier init
// ---------------------------------------------------------------------------
__global__ __launch_bounds__(256) void prep_kernel(
    const float* __restrict__ x, const float* __restrict__ W1,
    const float* __restrict__ b1, const float* __restrict__ W2,
    const float* __restrict__ op_emb,
    const int* __restrict__ tempers, const int* __restrict__ ops,
    float* __restrict__ state, unsigned short* __restrict__ W1b,
    unsigned short* __restrict__ W2b, float* __restrict__ c1,
    int* __restrict__ counts, int* __restrict__ lists,
    int* __restrict__ jobs, int* __restrict__ njobs, int* __restrict__ bar)
{
    const int bid = blockIdx.x;
    const int t = threadIdx.x;

    if (bid < 2304) {
        // ---- weight convert + swizzle ----
        const int mat = bid / 1152;           // 0: W1, 1: W2
        const int id  = bid % 1152;           // 36 experts * 8 kb * 4 jt
        const int e   = id / 32;
        const int sub = id % 32;
        const int kb  = sub / 4;
        const int jt  = sub % 4;
        const float* src = mat ? (W2 + e * 65536) : (W1 + e * 98304);
        unsigned short* dst = (mat ? W2b : W1b) + e * 65536;
        const int j  = jt * 64 + (t & 63);
        const int ks = (t >> 6) * 8;          // 8 consecutive k per thread
        short8 v;
        #pragma unroll
        for (int i = 0; i < 8; i++)
            v[i] = (short)f2bf(src[(kb * 32 + ks + i) * 256 + j]);  // coalesced across j
        *(short8*)(dst + (kb * 256 + j) * 32 + ks) = v;
    } else if (bid < 2340) {
        // ---- c1 precompute (fp32) ----
        const int e = bid - 2304;
        __shared__ float eb[128];
        if (t < 128) eb[t] = op_emb[e * 128 + t];
        __syncthreads();
        float acc = b1[e * 256 + t];
        const float* wp = W1 + e * 98304 + 256 * 256;  // emb rows of W1[e]
        #pragma unroll 4
        for (int k = 0; k < 128; k++)
            acc += eb[k] * wp[k * 256 + t];
        c1[e * 256 + t] = acc;
    } else if (bid < 2404) {
        // ---- state = x (f32 copy) ----
        const int cb = bid - 2340;
        const float4* xs = (const float4*)x;
        float4* ss = (float4*)state;
        #pragma unroll
        for (int p = 0; p < 4; p++) {
            int i4 = cb * 1024 + p * 256 + t;
            ss[i4] = xs[i4];
        }
    } else {
        // ---- routing (single block; cumulative-halt semantics) ----
        __shared__ int lc[HOPS * NEXP];
        if (t < HOPS * NEXP) lc[t] = 0;
        if (t == 0) bar[0] = 0;               // grid-barrier init (ws is poisoned)
        __syncthreads();
        for (int q = 0; q < 4; q++) {
            int n = q * 256 + t;
            bool act = true;
            for (int hop = 0; hop < HOPS; hop++) {
                int tt = tempers[hop * NTOK + n];
                int oo = ops[hop * NTOK + n];
                act = act && (tt != 12);       // 12 == halt; sticky
                if (act) {
                    int e = tt * 3 + oo;
                    int pos = atomicAdd(&lc[hop * NEXP + e], 1);
                    lists[(hop * NEXP + e) * NTOK + pos] = n;
                }
            }
        }
        __syncthreads();
        if (t < HOPS * NEXP) counts[t] = lc[t];
        // ---- job compaction: one thread per hop ----
        if (t < HOPS) {
            int hop = t, nj = 0;
            for (int e = 0; e < NEXP; e++) {
                int c = lc[hop * NEXP + e];
                for (int m0 = 0; m0 < c; m0 += 16)
                    jobs[hop * 128 + nj++] = (m0 << 8) | e;
            }
            njobs[hop] = nj;
        }
    }
}

// ---------------------------------------------------------------------------
// Grid barrier: monotonic counter, device-scope. All PGRID blocks co-resident
// (1 block/CU). Release: __threadfence (L2 writeback); acquire: __threadfence
// after spin (L1/L2 invalidate). Counter zeroed by prep (stream-ordered).
// ---------------------------------------------------------------------------
__device__ __forceinline__ void grid_barrier(int* bar, int target) {
    __syncthreads();
    if (threadIdx.x == 0) {
        __threadfence();
        __hip_atomic_fetch_add(bar, 1, __ATOMIC_RELEASE, __HIP_MEMORY_SCOPE_AGENT);
        while (__hip_atomic_load(bar, __ATOMIC_ACQUIRE, __HIP_MEMORY_SCOPE_AGENT) < target)
            __builtin_amdgcn_s_sleep(2);
        __threadfence();
    }
    __syncthreads();
}

// ---------------------------------------------------------------------------
// One (hop, expert, 16-token tile) job: fused 2-GEMM, identical math to r1.
// ---------------------------------------------------------------------------
__device__ __forceinline__ void do_job(
    int hop, int job, float* __restrict__ state,
    const unsigned short* __restrict__ W1b,
    const unsigned short* __restrict__ W2b,
    const float* __restrict__ c1, const float* __restrict__ b2,
    const int* __restrict__ counts, const int* __restrict__ lists,
    int* toks, unsigned short* Ab, unsigned short* Hb)
{
    const int e   = job & 0xFF;
    const int m0  = job >> 8;
    const int n_e = counts[hop * NEXP + e];
    const int mact = min(16, n_e - m0);
    const int t = threadIdx.x;

    __syncthreads();                       // protect toks/Ab reuse across jobs
    if (t < 16) toks[t] = (t < mact) ? lists[(hop * NEXP + e) * NTOK + m0 + t] : 0;
    __syncthreads();

    // ---- stage A tile: state rows (f32) -> bf16 in A-frag layout ----
    #pragma unroll
    for (int p = 0; p < 4; p++) {
        int idx = p * 256 + t;
        int m = idx >> 6;                  // token row 0..15
        int c4 = idx & 63;                 // float4 column
        int k = c4 * 4;
        float4 v = make_float4(0.f, 0.f, 0.f, 0.f);
        if (m < mact) v = *(const float4*)(state + toks[m] * 256 + k);
        int kb = k >> 5, g = (k >> 3) & 3, i = k & 7;
        unsigned short* d = Ab + kb * 512 + (g * 16 + m) * 8 + i;
        d[0] = f2bf(v.x); d[1] = f2bf(v.y); d[2] = f2bf(v.z); d[3] = f2bf(v.w);
    }
    __syncthreads();

    const int l = t & 63, w = t >> 6;
    const int col = l & 15, g = l >> 4;

    floatx4 acc[4];
    #pragma unroll
    for (int jt = 0; jt < 4; jt++) {
        float cv = c1[e * 256 + w * 64 + jt * 16 + col];
        acc[jt] = (floatx4){cv, cv, cv, cv};
    }
    // ---- GEMM1 ----
    const unsigned short* Wp = W1b + e * 65536;
    #pragma unroll
    for (int kb = 0; kb < 8; kb++) {
        short8 a = *(const short8*)(Ab + kb * 512 + l * 8);
        #pragma unroll
        for (int jt = 0; jt < 4; jt++) {
            int j = w * 64 + jt * 16 + col;
            short8 bfrg = *(const short8*)(Wp + (kb * 256 + j) * 32 + g * 8);
            acc[jt] = __builtin_amdgcn_mfma_f32_16x16x32_bf16(a, bfrg, acc[jt], 0, 0, 0);
        }
    }
    // ---- epilogue 1: relu -> Hb in A-frag layout ----
    #pragma unroll
    for (int jt = 0; jt < 4; jt++) {
        int kh = w * 64 + jt * 16 + col;
        int kb2 = kh >> 5, g2 = (kh >> 3) & 3, i2 = kh & 7;
        #pragma unroll
        for (int r = 0; r < 4; r++) {
            int m = g * 4 + r;             // D row
            float vv = acc[jt][r];
            vv = vv > 0.f ? vv : 0.f;
            Hb[kb2 * 512 + (g2 * 16 + m) * 8 + i2] = f2bf(vv);
        }
    }
    __syncthreads();

    #pragma unroll
    for (int jt = 0; jt < 4; jt++) {
        float bv = b2[e * 256 + w * 64 + jt * 16 + col];
        acc[jt] = (floatx4){bv, bv, bv, bv};
    }
    // ---- GEMM2 ----
    const unsigned short* Wp2 = W2b + e * 65536;
    #pragma unroll
    for (int kb = 0; kb < 8; kb++) {
        short8 a = *(const short8*)(Hb + kb * 512 + l * 8);
        #pragma unroll
        for (int jt = 0; jt < 4; jt++) {
            int j = w * 64 + jt * 16 + col;
            short8 bfrg = *(const short8*)(Wp2 + (kb * 256 + j) * 32 + g * 8);
            acc[jt] = __builtin_amdgcn_mfma_f32_16x16x32_bf16(a, bfrg, acc[jt], 0, 0, 0);
        }
    }
    // ---- epilogue 2: relu -> state (f32), only real rows ----
    #pragma unroll
    for (int jt = 0; jt < 4; jt++) {
        int j = w * 64 + jt * 16 + col;
        #pragma unroll
        for (int r = 0; r < 4; r++) {
            int m = g * 4 + r;
            if (m < mact) {
                float vv = acc[jt][r];
                state[toks[m] * 256 + j] = vv > 0.f ? vv : 0.f;
            }
        }
    }
}

// ---------------------------------------------------------------------------
// PERSISTENT: 4 hops (job-pulled) with grid barriers, then fused pool/LN/head.
// ---------------------------------------------------------------------------
__global__ __launch_bounds__(256) void persist_kernel(
    float* __restrict__ state,
    const unsigned short* __restrict__ W1b,
    const unsigned short* __restrict__ W2b,
    const float* __restrict__ c1, const float* __restrict__ b2,
    const int* __restrict__ counts, const int* __restrict__ lists,
    const int* __restrict__ jobs, const int* __restrict__ njobs,
    int* __restrict__ bar,
    const float* __restrict__ ln_g, const float* __restrict__ ln_b,
    const float* __restrict__ Wt, const float* __restrict__ bt,
    float* __restrict__ out)
{
    __shared__ int toks[16];
    __shared__ unsigned short Ab[4096];
    __shared__ unsigned short Hb[4096];

    for (int hop = 0; hop < HOPS; hop++) {
        const int nj = njobs[hop];
        for (int j = blockIdx.x; j < nj; j += PGRID)
            do_job(hop, jobs[hop * 128 + j], state, W1b, W2b, c1, b2,
                   counts, lists, toks, Ab, Hb);
        grid_barrier(bar, (hop + 1) * PGRID);
    }

    // ---- fused mean-pool -> LayerNorm -> head (blocks 0..127) ----
    const int b = blockIdx.x;
    if (b >= 128) return;
    const int t = threadIdx.x;
    float s = 0.f;
    #pragma unroll
    for (int p = 0; p < 8; p++) s += state[(b * 8 + p) * 256 + t];
    s *= 0.125f;

    float v1 = s, v2 = s * s;
    #pragma unroll
    for (int off = 32; off; off >>= 1) {
        v1 += __shfl_down(v1, off);
        v2 += __shfl_down(v2, off);
    }
    __shared__ float red[8];
    __shared__ float stats[2];
    const int w = t >> 6, l = t & 63;
    if (l == 0) { red[w] = v1; red[4 + w] = v2; }
    __syncthreads();
    if (t == 0) {
        float su = red[0] + red[1] + red[2] + red[3];
        float sq = red[4] + red[5] + red[6] + red[7];
        float mu = su * (1.0f / 256.0f);
        float var = sq * (1.0f / 256.0f) - mu * mu;
        stats[0] = mu;
        stats[1] = rsqrtf(var + 1e-5f);
    }
    __syncthreads();
    float normed = (s - stats[0]) * stats[1] * ln_g[t] + ln_b[t];

    __shared__ float pr[40];
    #pragma unroll
    for (int c = 0; c < 10; c++) {
        float pv = normed * Wt[t * 10 + c];
        #pragma unroll
        for (int off = 32; off; off >>= 1) pv += __shfl_down(pv, off);
        if (l == 0) pr[w * 10 + c] = pv;
    }
    __syncthreads();
    if (t < 10)
        out[b * 10 + t] = pr[t] + pr[10 + t] + pr[20 + t] + pr[30 + t] + bt[t];
}

extern "C" void kernel_launch(void* const* d_in, const int* in_sizes, int n_in,
                              void* d_out, int out_size, void* d_ws, size_t ws_size,
                              hipStream_t stream)
{
    const float* x      = (const float*)d_in[0];
    const float* W1     = (const float*)d_in[1];
    const float* b1     = (const float*)d_in[2];
    const float* W2     = (const float*)d_in[3];
    const float* b2     = (const float*)d_in[4];
    const float* op_emb = (const float*)d_in[5];
    const float* ln_g   = (const float*)d_in[6];
    const float* ln_b   = (const float*)d_in[7];
    const float* Wt     = (const float*)d_in[8];
    const float* bt     = (const float*)d_in[9];
    const int* tempers  = (const int*)d_in[10];
    const int* ops      = (const int*)d_in[11];

    char* ws = (char*)d_ws;
    float* state          = (float*)(ws + OFF_STATE);
    unsigned short* W1b   = (unsigned short*)(ws + OFF_W1B);
    unsigned short* W2b   = (unsigned short*)(ws + OFF_W2B);
    float* c1             = (float*)(ws + OFF_C1);
    int* counts           = (int*)(ws + OFF_COUNTS);
    int* lists            = (int*)(ws + OFF_LISTS);
    int* jobs             = (int*)(ws + OFF_JOBS);
    int* njobs            = (int*)(ws + OFF_NJ);
    int* bar              = (int*)(ws + OFF_BAR);
    float* out            = (float*)d_out;

    prep_kernel<<<2405, 256, 0, stream>>>(x, W1, b1, W2, op_emb, tempers, ops,
                                          state, W1b, W2b, c1, counts, lists,
                                          jobs, njobs, bar);
    persist_kernel<<<PGRID, 256, 0, stream>>>(state, W1b, W2b, c1, b2,
                                              counts, lists, jobs, njobs, bar,
                                              ln_g, ln_b, Wt, bt, out);
}

// Round 4
// 142.433 us; speedup vs baseline: 2.2407x; 2.2407x over previous
//
#include <hip/hip_runtime.h>

typedef __attribute__((ext_vector_type(8))) short short8;
typedef __attribute__((ext_vector_type(4))) float floatx4;

// Problem constants
#define NEXP   36          // 12 tempers * 3 ops
#define NTOK   1024        // 128 batch * 8 patches
#define HOPS   4

// Workspace layout (bytes)
#define OFF_STATE   0u          // 1024*256*4      = 1,048,576
#define OFF_W1B     1048576u    // 36*65536*2      = 4,718,592 (bf16, swizzled)
#define OFF_W2B     5767168u    // 36*65536*2      = 4,718,592
#define OFF_C1      10485760u   // 36*256*4        = 36,864
#define OFF_COUNTS  10522624u   // 4*36*4          = 576
#define OFF_LISTS   10523264u   // 4*36*1024*4     = 589,824
#define OFF_JOBS    11113088u   // 4*128*4         = 2,048
#define OFF_NJ      11115136u   // 4*4             = 16   (end ~11.1 MB)

__device__ __forceinline__ unsigned short f2bf(float f) {
    unsigned u = __float_as_uint(f);
    u += 0x7FFFu + ((u >> 16) & 1u);   // round-to-nearest-even
    return (unsigned short)(u >> 16);
}

// ---------------------------------------------------------------------------
// PREP: one kernel, block-role partitioned.
//  blocks [0,2304)    : convert W1(first 256 rows)/W2 -> bf16 in B-frag layout
//                       Wb[e][kb][j][k32],  kb=k/32, k32=k%32
//  blocks [2304,2340) : c1[e][j] = b1[e][j] + sum_k emb[e][k]*W1[e][256+k][j]
//  blocks [2340,2404) : copy x -> state (f32)
//  block  2404        : routing + job compaction
// ---------------------------------------------------------------------------
__global__ __launch_bounds__(256) void prep_kernel(
    const float* __restrict__ x, const float* __restrict__ W1,
    const float* __restrict__ b1, const float* __restrict__ W2,
    const float* __restrict__ op_emb,
    const int* __restrict__ tempers, const int* __restrict__ ops,
    float* __restrict__ state, unsigned short* __restrict__ W1b,
    unsigned short* __restrict__ W2b, float* __restrict__ c1,
    int* __restrict__ counts, int* __restrict__ lists,
    int* __restrict__ jobs, int* __restrict__ njobs)
{
    const int bid = blockIdx.x;
    const int t = threadIdx.x;

    if (bid < 2304) {
        // ---- weight convert + swizzle ----
        const int mat = bid / 1152;           // 0: W1, 1: W2
        const int id  = bid % 1152;           // 36 experts * 8 kb * 4 jt
        const int e   = id / 32;
        const int sub = id % 32;
        const int kb  = sub / 4;
        const int jt  = sub % 4;
        const float* src = mat ? (W2 + e * 65536) : (W1 + e * 98304);
        unsigned short* dst = (mat ? W2b : W1b) + e * 65536;
        const int j  = jt * 64 + (t & 63);
        const int ks = (t >> 6) * 8;          // 8 consecutive k per thread
        short8 v;
        #pragma unroll
        for (int i = 0; i < 8; i++)
            v[i] = (short)f2bf(src[(kb * 32 + ks + i) * 256 + j]);  // coalesced across j
        *(short8*)(dst + (kb * 256 + j) * 32 + ks) = v;
    } else if (bid < 2340) {
        // ---- c1 precompute (fp32) ----
        const int e = bid - 2304;
        __shared__ float eb[128];
        if (t < 128) eb[t] = op_emb[e * 128 + t];
        __syncthreads();
        float acc = b1[e * 256 + t];
        const float* wp = W1 + e * 98304 + 256 * 256;  // emb rows of W1[e]
        #pragma unroll 4
        for (int k = 0; k < 128; k++)
            acc += eb[k] * wp[k * 256 + t];
        c1[e * 256 + t] = acc;
    } else if (bid < 2404) {
        // ---- state = x (f32 copy) ----
        const int cb = bid - 2340;
        const float4* xs = (const float4*)x;
        float4* ss = (float4*)state;
        #pragma unroll
        for (int p = 0; p < 4; p++) {
            int i4 = cb * 1024 + p * 256 + t;
            ss[i4] = xs[i4];
        }
    } else {
        // ---- routing (single block; cumulative-halt semantics) ----
        __shared__ int lc[HOPS * NEXP];
        if (t < HOPS * NEXP) lc[t] = 0;
        __syncthreads();
        for (int q = 0; q < 4; q++) {
            int n = q * 256 + t;
            bool act = true;
            for (int hop = 0; hop < HOPS; hop++) {
                int tt = tempers[hop * NTOK + n];
                int oo = ops[hop * NTOK + n];
                act = act && (tt != 12);       // 12 == halt; sticky
                if (act) {
                    int e = tt * 3 + oo;
                    int pos = atomicAdd(&lc[hop * NEXP + e], 1);
                    lists[(hop * NEXP + e) * NTOK + pos] = n;
                }
            }
        }
        __syncthreads();
        if (t < HOPS * NEXP) counts[t] = lc[t];
        // ---- job compaction: one thread per hop; job = (m0<<8)|e ----
        if (t < HOPS) {
            int hop = t, nj = 0;
            for (int e = 0; e < NEXP; e++) {
                int c = lc[hop * NEXP + e];
                for (int m0 = 0; m0 < c; m0 += 16)
                    jobs[hop * 128 + nj++] = (m0 << 8) | e;
            }
            njobs[hop] = nj;
        }
    }
}

// ---------------------------------------------------------------------------
// HOP: one job = (expert, 16-token tile), 1024 threads = 16 waves.
// Wave w owns output columns [w*16, w*16+16) — ONE 16x16 MFMA col-tile per
// GEMM, so per-wave weight traffic is 8 KB/GEMM and the block has 16 waves'
// worth of loads in flight (the r1->r3 fix: latency-bound per-block path).
//  GEMM1: h = relu(state_bf16 @ W1b + c1)   (c1 folds emb part + b1)
//  GEMM2: y = relu(h_bf16 @ W2b + b2)  -> state (f32)
// MFMA maps (m89): A[m=l&15][k=(l>>4)*8+i]; D col=l&15, row=(l>>4)*4+reg.
// ---------------------------------------------------------------------------
__global__ __launch_bounds__(1024) void hop_kernel(
    float* __restrict__ state,
    const unsigned short* __restrict__ W1b,
    const unsigned short* __restrict__ W2b,
    const float* __restrict__ c1, const float* __restrict__ b2,
    const int* __restrict__ counts, const int* __restrict__ lists,
    const int* __restrict__ jobs, const int* __restrict__ njobs, int hop)
{
    if (blockIdx.x >= njobs[hop]) return;  // uniform early-exit
    const int job = jobs[hop * 128 + blockIdx.x];
    const int e   = job & 0xFF;
    const int m0  = job >> 8;
    const int n_e = counts[hop * NEXP + e];
    const int mact = min(16, n_e - m0);

    __shared__ int toks[16];
    __shared__ unsigned short Ab[4096];    // [kb][lane][8] bf16, 8 KB
    __shared__ unsigned short Hb[4096];    // 8 KB

    const int t = threadIdx.x;
    if (t < 16) toks[t] = (t < mact) ? lists[(hop * NEXP + e) * NTOK + m0 + t] : 0;
    __syncthreads();

    // ---- stage A tile: state rows (f32) -> bf16 in A-frag layout ----
    {
        int m = t >> 6;                    // token row 0..15
        int k = (t & 63) * 4;              // float4 column
        float4 v = make_float4(0.f, 0.f, 0.f, 0.f);
        if (m < mact) v = *(const float4*)(state + toks[m] * 256 + k);
        int kb = k >> 5, g = (k >> 3) & 3, i = k & 7;
        unsigned short* d = Ab + kb * 512 + (g * 16 + m) * 8 + i;
        d[0] = f2bf(v.x); d[1] = f2bf(v.y); d[2] = f2bf(v.z); d[3] = f2bf(v.w);
    }
    __syncthreads();

    const int l = t & 63, w = t >> 6;      // wave 0..15
    const int col = l & 15, g = l >> 4;
    const int j = w * 16 + col;            // this wave's output column

    floatx4 acc;
    {
        float cv = c1[e * 256 + j];
        acc = (floatx4){cv, cv, cv, cv};
    }
    // ---- GEMM1 ----
    const unsigned short* Wp = W1b + e * 65536;
    #pragma unroll
    for (int kb = 0; kb < 8; kb++) {
        short8 a = *(const short8*)(Ab + kb * 512 + l * 8);
        short8 bfrg = *(const short8*)(Wp + (kb * 256 + j) * 32 + g * 8);
        acc = __builtin_amdgcn_mfma_f32_16x16x32_bf16(a, bfrg, acc, 0, 0, 0);
    }
    // ---- epilogue 1: relu -> Hb in A-frag layout (h-dim becomes K) ----
    {
        int kh = j;                        // h column this wave produced
        int kb2 = kh >> 5, g2 = (kh >> 3) & 3, i2 = kh & 7;
        #pragma unroll
        for (int r = 0; r < 4; r++) {
            int m = g * 4 + r;             // D row (token)
            float vv = acc[r];
            vv = vv > 0.f ? vv : 0.f;
            Hb[kb2 * 512 + (g2 * 16 + m) * 8 + i2] = f2bf(vv);
        }
    }
    __syncthreads();

    {
        float bv = b2[e * 256 + j];
        acc = (floatx4){bv, bv, bv, bv};
    }
    // ---- GEMM2 ----
    const unsigned short* Wp2 = W2b + e * 65536;
    #pragma unroll
    for (int kb = 0; kb < 8; kb++) {
        short8 a = *(const short8*)(Hb + kb * 512 + l * 8);
        short8 bfrg = *(const short8*)(Wp2 + (kb * 256 + j) * 32 + g * 8);
        acc = __builtin_amdgcn_mfma_f32_16x16x32_bf16(a, bfrg, acc, 0, 0, 0);
    }
    // ---- epilogue 2: relu -> state (f32), only real rows ----
    #pragma unroll
    for (int r = 0; r < 4; r++) {
        int m = g * 4 + r;
        if (m < mact) {
            float vv = acc[r];
            state[toks[m] * 256 + j] = vv > 0.f ? vv : 0.f;
        }
    }
}

// ---------------------------------------------------------------------------
// FINAL: mean-pool 8 patches -> LayerNorm -> 10-class head. One block/batch.
// ---------------------------------------------------------------------------
__global__ __launch_bounds__(256) void final_kernel(
    const float* __restrict__ state, const float* __restrict__ ln_g,
    const float* __restrict__ ln_b, const float* __restrict__ Wt,
    const float* __restrict__ bt, float* __restrict__ out)
{
    const int b = blockIdx.x, t = threadIdx.x;
    float s = 0.f;
    #pragma unroll
    for (int p = 0; p < 8; p++) s += state[(b * 8 + p) * 256 + t];
    s *= 0.125f;

    float v1 = s, v2 = s * s;
    #pragma unroll
    for (int off = 32; off; off >>= 1) {
        v1 += __shfl_down(v1, off);
        v2 += __shfl_down(v2, off);
    }
    __shared__ float red[8];
    __shared__ float stats[2];
    const int w = t >> 6, l = t & 63;
    if (l == 0) { red[w] = v1; red[4 + w] = v2; }
    __syncthreads();
    if (t == 0) {
        float su = red[0] + red[1] + red[2] + red[3];
        float sq = red[4] + red[5] + red[6] + red[7];
        float mu = su * (1.0f / 256.0f);
        float var = sq * (1.0f / 256.0f) - mu * mu;
        stats[0] = mu;
        stats[1] = rsqrtf(var + 1e-5f);
    }
    __syncthreads();
    float normed = (s - stats[0]) * stats[1] * ln_g[t] + ln_b[t];

    __shared__ float pr[40];
    #pragma unroll
    for (int c = 0; c < 10; c++) {
        float pv = normed * Wt[t * 10 + c];
        #pragma unroll
        for (int off = 32; off; off >>= 1) pv += __shfl_down(pv, off);
        if (l == 0) pr[w * 10 + c] = pv;
    }
    __syncthreads();
    if (t < 10)
        out[b * 10 + t] = pr[t] + pr[10 + t] + pr[20 + t] + pr[30 + t] + bt[t];
}

extern "C" void kernel_launch(void* const* d_in, const int* in_sizes, int n_in,
                              void* d_out, int out_size, void* d_ws, size_t ws_size,
                              hipStream_t stream)
{
    const float* x      = (const float*)d_in[0];
    const float* W1     = (const float*)d_in[1];
    const float* b1     = (const float*)d_in[2];
    const float* W2     = (const float*)d_in[3];
    const float* b2     = (const float*)d_in[4];
    const float* op_emb = (const float*)d_in[5];
    const float* ln_g   = (const float*)d_in[6];
    const float* ln_b   = (const float*)d_in[7];
    const float* Wt     = (const float*)d_in[8];
    const float* bt     = (const float*)d_in[9];
    const int* tempers  = (const int*)d_in[10];
    const int* ops      = (const int*)d_in[11];

    char* ws = (char*)d_ws;
    float* state          = (float*)(ws + OFF_STATE);
    unsigned short* W1b   = (unsigned short*)(ws + OFF_W1B);
    unsigned short* W2b   = (unsigned short*)(ws + OFF_W2B);
    float* c1             = (float*)(ws + OFF_C1);
    int* counts           = (int*)(ws + OFF_COUNTS);
    int* lists            = (int*)(ws + OFF_LISTS);
    int* jobs             = (int*)(ws + OFF_JOBS);
    int* njobs            = (int*)(ws + OFF_NJ);
    float* out            = (float*)d_out;

    prep_kernel<<<2405, 256, 0, stream>>>(x, W1, b1, W2, op_emb, tempers, ops,
                                          state, W1b, W2b, c1, counts, lists,
                                          jobs, njobs);
    for (int hop = 0; hop < HOPS; hop++)
        hop_kernel<<<128, 1024, 0, stream>>>(state, W1b, W2b, c1, b2,
                                             counts, lists, jobs, njobs, hop);
    final_kernel<<<128, 256, 0, stream>>>(state, ln_g, ln_b, Wt, bt, out);
}